// Round 6
// baseline (14.100 us; speedup 1.0000x reference)
//
#include <hip/hip_runtime.h>

// Dist_Conv2D: out[b,f,h,w] = max_{c,i,j} |W[f, c*9+i*3+j] - x_pad[b,c,h+i,w+j]| + bias[f]
// x: (4,16,64,64) f32, W: (64,144) f32, bias: (64,) f32, out: (4,64,64,64) f32
// replicate pad 1 on each side of H,W.
//
// R6: replace __shfl (ds_bpermute, LDS pipe, lgkmcnt-entangled with SMEM weight
// s_loads) with DPP wave shifts (VALU pipe, no lgkmcnt). bound_ctrl=false +
// old=v makes boundary lanes keep own value == replicate padding at w=0/63.
//   0x138 = wave_shr:1 (lane i <- lane i-1, left neighbor)
//   0x130 = wave_shl:1 (lane i <- lane i+1, right neighbor)
// Keep: SGPR-provable f0 (R4), FCHUNK=4, no min-waves bound (R2 lesson).

#define BB 4
#define CC 16
#define HH 64
#define WW 64
#define FF 64
#define FCHUNK 4

#define DPP_LEFT(v)  __int_as_float(__builtin_amdgcn_update_dpp(            \
        __float_as_int(v), __float_as_int(v), 0x138, 0xf, 0xf, false))
#define DPP_RIGHT(v) __int_as_float(__builtin_amdgcn_update_dpp(            \
        __float_as_int(v), __float_as_int(v), 0x130, 0xf, 0xf, false))

__global__ __launch_bounds__(256) void dist_conv2d_kernel(
    const float* __restrict__ x,
    const float* __restrict__ wgt,
    const float* __restrict__ bias,
    float* __restrict__ out) {
    // block = 256 threads = (h_lo(2) | w(6)); blockIdx bits: fc(4)|b(2)|h_hi(4)
    int w  = threadIdx.x & 63;             // lane id
    int h  = ((blockIdx.x & 15) << 2) | (threadIdx.x >> 6);
    int b  = (blockIdx.x >> 4) & 3;        // SGPR
    int fc = blockIdx.x >> 6;              // SGPR, 0..15
    int f0 = fc * FCHUNK;                  // SGPR

    // replicate-pad clamped row indices (columns handled by DPP boundary rule)
    int r0 = h - 1; if (r0 < 0) r0 = 0;
    int r2 = h + 1; if (r2 > HH - 1) r2 = HH - 1;
    int row0 = r0 * WW + w, row1 = h * WW + w, row2 = r2 * WW + w;

    float dist[FCHUNK];
#pragma unroll
    for (int i = 0; i < FCHUNK; ++i) dist[i] = 0.0f;

    const float* xb    = x + b * (CC * HH * WW);
    const float* wbase = wgt + f0 * (CC * 9);        // SGPR base -> s_load

#pragma unroll 4
    for (int c = 0; c < CC; ++c) {
        const float* xc = xb + c * (HH * WW);
        float v0 = xc[row0], v1 = xc[row1], v2 = xc[row2];   // 3 loads/channel
        float p[9];
        p[0] = DPP_LEFT(v0);  p[1] = v0;  p[2] = DPP_RIGHT(v0);
        p[3] = DPP_LEFT(v1);  p[4] = v1;  p[5] = DPP_RIGHT(v1);
        p[6] = DPP_LEFT(v2);  p[7] = v2;  p[8] = DPP_RIGHT(v2);
#pragma unroll
        for (int fi = 0; fi < FCHUNK; ++fi) {
            const float* wrow = wbase + fi * (CC * 9) + c * 9;   // uniform -> s_load
#pragma unroll
            for (int k = 0; k < 9; ++k) {
                float d = p[k] - wrow[k];
                dist[fi] = fmaxf(dist[fi], fabsf(d));
            }
        }
    }

    float* ob = out + ((b * FF + f0) * HH + h) * WW + w;
#pragma unroll
    for (int fi = 0; fi < FCHUNK; ++fi) {
        ob[fi * (HH * WW)] = dist[fi] + bias[f0 + fi];   // bias: s_load
    }
}

extern "C" void kernel_launch(void* const* d_in, const int* in_sizes, int n_in,
                              void* d_out, int out_size, void* d_ws, size_t ws_size,
                              hipStream_t stream) {
    const float* x    = (const float*)d_in[0];
    const float* wgt  = (const float*)d_in[1];
    const float* bias = (const float*)d_in[2];
    float* out = (float*)d_out;

    const int total = (FF / FCHUNK) * BB * HH * WW;  // 262144 threads, 1024 blocks
    dist_conv2d_kernel<<<total / 256, 256, 0, stream>>>(x, wgt, bias, out);
}

// Round 7
// 13.815 us; speedup vs baseline: 1.0206x; 1.0206x over previous
//
#include <hip/hip_runtime.h>

// Dist_Conv2D: out[b,f,h,w] = max_{c,i,j} |W[f, c*9+i*3+j] - x_pad[b,c,h+i,w+j]| + bias[f]
// x: (4,16,64,64) f32, W: (64,144) f32, bias: (64,) f32, out: (4,64,64,64) f32
// replicate pad 1 on each side of H,W.
//
// R7: FULL unroll of the c-loop (16x). R3/R5/R6 nulls showed the stall is
// per-iteration latency exposure (load->wait->compute chain repeated 16x with
// a shallow scheduling window), not TLP, not VMEM count, not lgkm entanglement.
// Full unroll lets the compiler hoist all 48 x-loads arbitrarily early.
// Keep: DPP column neighbors (VALU pipe, replicate-pad boundary semantics),
// SGPR-provable f0 (R4), no min-waves bound (R2 lesson).

#define BB 4
#define CC 16
#define HH 64
#define WW 64
#define FF 64
#define FCHUNK 4

#define DPP_LEFT(v)  __int_as_float(__builtin_amdgcn_update_dpp(            \
        __float_as_int(v), __float_as_int(v), 0x138, 0xf, 0xf, false))
#define DPP_RIGHT(v) __int_as_float(__builtin_amdgcn_update_dpp(            \
        __float_as_int(v), __float_as_int(v), 0x130, 0xf, 0xf, false))

__global__ __launch_bounds__(256) void dist_conv2d_kernel(
    const float* __restrict__ x,
    const float* __restrict__ wgt,
    const float* __restrict__ bias,
    float* __restrict__ out) {
    // block = 256 threads = (h_lo(2) | w(6)); blockIdx bits: fc(4)|b(2)|h_hi(4)
    int w  = threadIdx.x & 63;             // lane id
    int h  = ((blockIdx.x & 15) << 2) | (threadIdx.x >> 6);
    int b  = (blockIdx.x >> 4) & 3;        // SGPR
    int fc = blockIdx.x >> 6;              // SGPR, 0..15
    int f0 = fc * FCHUNK;                  // SGPR

    // replicate-pad clamped row indices (columns handled by DPP boundary rule)
    int r0 = h - 1; if (r0 < 0) r0 = 0;
    int r2 = h + 1; if (r2 > HH - 1) r2 = HH - 1;
    int row0 = r0 * WW + w, row1 = h * WW + w, row2 = r2 * WW + w;

    float dist[FCHUNK];
#pragma unroll
    for (int i = 0; i < FCHUNK; ++i) dist[i] = 0.0f;

    const float* xb    = x + b * (CC * HH * WW);
    const float* wbase = wgt + f0 * (CC * 9);        // SGPR base -> s_load

#pragma unroll
    for (int c = 0; c < CC; ++c) {
        const float* xc = xb + c * (HH * WW);
        float v0 = xc[row0], v1 = xc[row1], v2 = xc[row2];   // 3 loads/channel
        float p[9];
        p[0] = DPP_LEFT(v0);  p[1] = v0;  p[2] = DPP_RIGHT(v0);
        p[3] = DPP_LEFT(v1);  p[4] = v1;  p[5] = DPP_RIGHT(v1);
        p[6] = DPP_LEFT(v2);  p[7] = v2;  p[8] = DPP_RIGHT(v2);
#pragma unroll
        for (int fi = 0; fi < FCHUNK; ++fi) {
            const float* wrow = wbase + fi * (CC * 9) + c * 9;   // uniform -> s_load
#pragma unroll
            for (int k = 0; k < 9; ++k) {
                float d = p[k] - wrow[k];
                dist[fi] = fmaxf(dist[fi], fabsf(d));
            }
        }
    }

    float* ob = out + ((b * FF + f0) * HH + h) * WW + w;
#pragma unroll
    for (int fi = 0; fi < FCHUNK; ++fi) {
        ob[fi * (HH * WW)] = dist[fi] + bias[f0 + fi];   // bias: s_load
    }
}

extern "C" void kernel_launch(void* const* d_in, const int* in_sizes, int n_in,
                              void* d_out, int out_size, void* d_ws, size_t ws_size,
                              hipStream_t stream) {
    const float* x    = (const float*)d_in[0];
    const float* wgt  = (const float*)d_in[1];
    const float* bias = (const float*)d_in[2];
    float* out = (float*)d_out;

    const int total = (FF / FCHUNK) * BB * HH * WW;  // 262144 threads, 1024 blocks
    dist_conv2d_kernel<<<total / 256, 256, 0, stream>>>(x, wgt, bias, out);
}